// Round 7
// baseline (546.487 us; speedup 1.0000x reference)
//
#include <hip/hip_runtime.h>
#include <stdint.h>

// Problem constants
constexpr int NB = 8;      // batch
constexpr int NS = 2048;   // nodes
constexpr int ND = 256;    // in dim
constexpr int NDO = 256;   // out dim
constexpr int NL = 8;      // labels
constexpr int NE = 32768;  // edges per batch
constexpr int NG = NS * NL;        // groups (t,l) per batch = 16384
constexpr int KH = 2112;           // H row: 2048 data + 8 cnt + 56 zero (mult of 64)
constexpr int NBLK = 512;          // persistent grid: 2 blocks/CU guaranteed resident

typedef __attribute__((ext_vector_type(8))) short bf16x8;
typedef __attribute__((ext_vector_type(4))) float f32x4;
typedef unsigned int u32;

__device__ __forceinline__ float bf2f(uint32_t u) {
    return __uint_as_float(u << 16);
}
__device__ __forceinline__ uint32_t f2bf(float f) {
    uint32_t x = __float_as_uint(f);
    return (x + 0x7fffu + ((x >> 16) & 1u)) >> 16;
}

// async global->LDS, 16B per lane; lds ptr must be wave-uniform (HW adds lane*16)
__device__ __forceinline__ void gl_lds16(const void* gptr, void* lptr) {
    __builtin_amdgcn_global_load_lds(
        (const __attribute__((address_space(1))) u32*)gptr,
        (__attribute__((address_space(3))) u32*)lptr, 16, 0, 0);
}

// single-use grid barrier (bar[idx] pre-zeroed by memset each launch).
// Device-scope release add + acquire spin -> cross-XCD safe.
__device__ __forceinline__ void grid_barrier(int* bar, int idx) {
    __syncthreads();
    if (threadIdx.x == 0) {
        __hip_atomic_fetch_add(&bar[idx], 1, __ATOMIC_RELEASE, __HIP_MEMORY_SCOPE_AGENT);
        while (__hip_atomic_load(&bar[idx], __ATOMIC_ACQUIRE, __HIP_MEMORY_SCOPE_AGENT) < NBLK)
            __builtin_amdgcn_s_sleep(8);
    }
    __syncthreads();
}

__device__ __forceinline__ void accum4(float4& a, uint2 v) {
    a.x += bf2f(v.x & 0xffffu);
    a.y += bf2f(v.x >> 16);
    a.z += bf2f(v.y & 0xffffu);
    a.w += bf2f(v.y >> 16);
}

__global__ __launch_bounds__(256, 2) void fused_kernel(
    const float* __restrict__ x, const int* __restrict__ esrc,
    const int* __restrict__ etgt, const int* __restrict__ elab,
    const float* __restrict__ W, const float* __restrict__ bias,
    ushort* __restrict__ xb, ushort* __restrict__ wt2, ushort* __restrict__ H,
    int* __restrict__ counts, int* __restrict__ offs, int* __restrict__ sorted,
    float* __restrict__ out, int* __restrict__ bar) {
    __shared__ ushort smem[4096 + 8192];   // 24 KB: gemm As|Bs; scan reuses head
    int tid = threadIdx.x, bid = blockIdx.x;
    int gtid = bid * 256 + tid;            // < 131072
    int lane = tid & 63;

    // ================= phase A: prep =================
    for (int i = gtid; i < NB * NS * ND / 4; i += NBLK * 256) {
        float4 v = ((const float4*)x)[i];
        ushort4 o;
        o.x = (ushort)f2bf(v.x); o.y = (ushort)f2bf(v.y);
        o.z = (ushort)f2bf(v.z); o.w = (ushort)f2bf(v.w);
        ((ushort4*)xb)[i] = o;
    }
    if (bid < 256) {                       // wt2 = [W;bias;0]^T, one block per col
        int o = bid;
        for (int k = tid; k < KH; k += 256) {
            float v = 0.f;
            if (k < NL * ND) v = W[(size_t)k * NDO + o];
            else if (k < NL * ND + NL) v = bias[(k - NL * ND) * NDO + o];
            wt2[(size_t)o * KH + k] = (ushort)f2bf(v);
        }
    }
    if (gtid < NB * NG / 4)                // zero counts
        ((int4*)counts)[gtid] = make_int4(0, 0, 0, 0);
    grid_barrier(bar, 0);

    // ================= phase B: histogram =================
    for (int i = gtid; i < NB * NE; i += NBLK * 256) {
        int b = i >> 15;
        atomicAdd(&counts[b * NG + etgt[i] * NL + elab[i]], 1);
    }
    grid_barrier(bar, 1);

    // ================= phase C: per-batch exclusive scan (8 blocks) =========
    if (bid < 8) {
        int b = bid;
        const int4* c4 = (const int4*)(counts + b * NG);
        int4 v[16];
        int base4 = tid * 16;
        int s = 0;
        for (int i = 0; i < 16; i++) {
            v[i] = c4[base4 + i];
            s += v[i].x + v[i].y + v[i].z + v[i].w;
        }
        int wv = tid >> 6;
        int incl = s;
        for (int d = 1; d < 64; d <<= 1) {
            int u = __shfl_up(incl, d);
            if (lane >= d) incl += u;
        }
        int* wsum = (int*)smem;
        if (lane == 63) wsum[wv] = incl;
        __syncthreads();
        int wb = 0;
        for (int w = 0; w < wv; w++) wb += wsum[w];
        int run = wb + incl - s;
        int4* o4 = (int4*)(offs + b * NG);
        for (int i = 0; i < 16; i++) {
            int4 o;
            o.x = run; o.y = o.x + v[i].x; o.z = o.y + v[i].y; o.w = o.z + v[i].z;
            run = o.w + v[i].w;
            o4[base4 + i] = o;
        }
    }
    grid_barrier(bar, 2);

    // ================= phase D: placement (counting sort) =================
    // cursor = counts reused? no: atomically bump a copy -> use counts as cursor
    // (counts still needed later for aggregate? aggregate uses n = offs[g+1]-offs[g]
    //  style? we kept counts; use atomicAdd on a cursor derived from offs via
    //  separate pass) -- simplest: bump offs copy stored in counts after saving.
    // Here: place uses atomicAdd on 'counts' REPURPOSED as cursor, initialized
    // from offs. First copy offs->counts (cursor), then place.
    for (int i = gtid; i < NB * NG / 4; i += NBLK * 256)
        ((int4*)counts)[i] = ((const int4*)offs)[i];   // wait-free copy (counts now = cursor base)
    grid_barrier(bar, 3);
    for (int i = gtid; i < NB * NE; i += NBLK * 256) {
        int b = i >> 15;
        int g = b * NG + etgt[i] * NL + elab[i];
        int p = atomicAdd(&counts[g], 1);              // counts acts as cursor
        sorted[b * NE + p] = esrc[i];
    }
    grid_barrier(bar, 4);
    // after placement: counts[g] == offs[g] + n[g]  (i.e. end offset) -- aggregate
    // derives n = counts[g] - offs[g].

    // ================= phase E: aggregate (2048 waves x 64 groups) =========
    {
        int wid = gtid >> 6;               // 0..2047
        int g0 = wid * 64;
        int b = g0 >> 14;
        const int* sortb = sorted + (size_t)b * NE;
        int myo = offs[g0 + lane];
        int myn = counts[g0 + lane] - myo; // end - start
        int winBase = __shfl(myo, 0);
        int widx = sortb[min(winBase + lane, NE - 1)];
        const ushort* xbb = xb + (size_t)b * NS * ND;

        for (int j = 0; j < 64; j++) {
            int n = __shfl(myn, j);
            int off = __shfl(myo, j);
            float4 a0 = {0.f, 0.f, 0.f, 0.f};
            float4 a1 = {0.f, 0.f, 0.f, 0.f};
            int pos = off, rem = n;
            while (rem > 0) {
                int need = (rem >= 2) ? pos + 1 : pos;
                if (need >= winBase + 64) {
                    winBase = pos;
                    widx = sortb[min(winBase + lane, NE - 1)];
                }
                if (rem >= 2) {
                    int s0 = __shfl(widx, pos - winBase);
                    int s1 = __shfl(widx, pos + 1 - winBase);
                    uint2 v0 = ((const uint2*)(xbb + (size_t)s0 * ND))[lane];
                    uint2 v1 = ((const uint2*)(xbb + (size_t)s1 * ND))[lane];
                    accum4(a0, v0);
                    accum4(a1, v1);
                    pos += 2; rem -= 2;
                } else {
                    int s0 = __shfl(widx, pos - winBase);
                    uint2 v0 = ((const uint2*)(xbb + (size_t)s0 * ND))[lane];
                    accum4(a0, v0);
                    pos += 1; rem -= 1;
                }
            }
            a0.x += a1.x; a0.y += a1.y; a0.z += a1.z; a0.w += a1.w;
            int g = g0 + j;
            int t = (g & (NG - 1)) >> 3, l = g & 7;
            ushort* hrow = H + ((size_t)(b * NS + t)) * KH;
            uint2 o;
            o.x = f2bf(a0.x) | (f2bf(a0.y) << 16);
            o.y = f2bf(a0.z) | (f2bf(a0.w) << 16);
            ((uint2*)(hrow + l * ND))[lane] = o;
            if (lane == 0) hrow[NL * ND + l] = (ushort)f2bf((float)n);
            if (l == 0 && lane < 56) hrow[NL * ND + NL + lane] = 0;
        }
    }
    grid_barrier(bar, 5);

    // ================= phase F: GEMM out = relu(H @ wt2^T) =================
    // 64x128 tile, 512 tiles == 512 blocks. BK=64, XOR-swizzled LDS (R6).
    {
        int n0 = (bid & 1) * 128;
        int m0 = (bid >> 1) * 64;
        ushort* As = smem;                 //  8 KB (512 slots)
        ushort* Bs = smem + 4096;          // 16 KB (1024 slots)

        int wave = __builtin_amdgcn_readfirstlane(tid >> 6);
        int wm = wave & 1, wn = wave >> 1;
        int ln = lane & 15, quad = lane >> 4;

        f32x4 acc[2][4] = {};

        const ushort* Ag = H + (size_t)m0 * KH;
        const ushort* Bg = wt2 + (size_t)n0 * KH;
        int sa0 = wave * 128 + lane;
        int sb0 = wave * 256 + lane;

        for (int k0 = 0; k0 < KH; k0 += 64) {
            for (int p = 0; p < 2; p++) {
                int s = sa0 + p * 64;
                int r = s >> 3, cg = (s & 7) ^ (r & 7);
                gl_lds16(Ag + (size_t)r * KH + k0 + cg * 8, &As[(wave * 128 + p * 64) * 8]);
            }
            for (int p = 0; p < 4; p++) {
                int s = sb0 + p * 64;
                int r = s >> 3, cg = (s & 7) ^ (r & 7);
                gl_lds16(Bg + (size_t)r * KH + k0 + cg * 8, &Bs[(wave * 256 + p * 64) * 8]);
            }
            __syncthreads();

            for (int h = 0; h < 2; h++) {
                bf16x8 af[2], bfr[4];
                for (int i = 0; i < 2; i++) {
                    int r = wm * 32 + i * 16 + ln;
                    int c = (h * 4 + quad) ^ (r & 7);
                    af[i] = *(const bf16x8*)&As[(r * 8 + c) * 8];
                }
                for (int j = 0; j < 4; j++) {
                    int r = wn * 64 + j * 16 + ln;
                    int c = (h * 4 + quad) ^ (r & 7);
                    bfr[j] = *(const bf16x8*)&Bs[(r * 8 + c) * 8];
                }
                for (int i = 0; i < 2; i++)
                    for (int j = 0; j < 4; j++)
                        acc[i][j] = __builtin_amdgcn_mfma_f32_16x16x32_bf16(af[i], bfr[j], acc[i][j], 0, 0, 0);
            }
            __syncthreads();
        }

        for (int j = 0; j < 4; j++) {
            int col = n0 + wn * 64 + j * 16 + ln;
            for (int i = 0; i < 2; i++) {
                int rbase = m0 + wm * 32 + i * 16 + quad * 4;
                for (int rr = 0; rr < 4; rr++) {
                    out[(size_t)(rbase + rr) * NDO + col] = fmaxf(acc[i][j][rr], 0.f);
                }
            }
        }
    }
}

extern "C" void kernel_launch(void* const* d_in, const int* in_sizes, int n_in,
                              void* d_out, int out_size, void* d_ws, size_t ws_size,
                              hipStream_t stream) {
    const float* x    = (const float*)d_in[0];
    const int*   esrc = (const int*)d_in[1];
    const int*   etgt = (const int*)d_in[2];
    const int*   elab = (const int*)d_in[3];
    const float* W    = (const float*)d_in[4];
    const float* bias = (const float*)d_in[5];
    float* out = (float*)d_out;

    char* ws = (char*)d_ws;
    ushort* xb     = (ushort*)(ws);                    //  8 MB: x bf16
    ushort* wt2    = (ushort*)(ws + 8388608);          //  ~1.03 MB: [W;bias;0]^T bf16
    ushort* H      = (ushort*)(ws + 10485760);         //  69.2 MB: aggregated features
    int*    counts = (int*)(ws + 79691776);            // 512 KB (doubles as cursor)
    int*    offs   = (int*)(ws + 80216064);            // 512 KB
    int*    sorted = (int*)(ws + 80740352);            //   1 MB
    int*    bar    = (int*)(ws + 81788928);            //  32 B barrier counters

    hipMemsetAsync(bar, 0, 8 * sizeof(int), stream);
    fused_kernel<<<NBLK, 256, 0, stream>>>(x, esrc, etgt, elab, W, bias,
                                           xb, wt2, H, counts, offs, sorted,
                                           out, bar);
}